// Round 3
// baseline (1970.501 us; speedup 1.0000x reference)
//
#include <hip/hip_runtime.h>
#include <hip/hip_bf16.h>

// Problem constants
#define BB 16
#define SS 512
#define DD 768
#define HH 8
#define VV 100
#define FF 2048
#define LL 6
#define DHH 96
#define TT (BB * SS)  // 8192 token rows
#define BH (BB * HH)  // 128 (batch,head) pairs

typedef __bf16 bf16x8 __attribute__((ext_vector_type(8)));
typedef float f32x4 __attribute__((ext_vector_type(4)));
typedef __hip_bfloat16 bf16_t;

// async global->LDS, 16B per lane; deposit = wave-uniform lds base + lane*16
__device__ __forceinline__ void load_lds16(const void* g, void* l) {
    __builtin_amdgcn_global_load_lds(
        (const __attribute__((address_space(1))) void*)g,
        (__attribute__((address_space(3))) void*)l, 16, 0, 0);
}

// ---------------------------------------------------------------------------
// fp32 -> bf16 conversion, 8 elements/thread (all sizes are %8==0)
// ---------------------------------------------------------------------------
__global__ void cvt8_kernel(const float4* __restrict__ s, uint4* __restrict__ d, int n8) {
    int i = blockIdx.x * blockDim.x + threadIdx.x;
    int stride = gridDim.x * blockDim.x;
    for (; i < n8; i += stride) {
        float4 x0 = s[2 * i], x1 = s[2 * i + 1];
        union { uint4 v; bf16_t h[8]; } o;
        o.h[0] = __float2bfloat16(x0.x);
        o.h[1] = __float2bfloat16(x0.y);
        o.h[2] = __float2bfloat16(x0.z);
        o.h[3] = __float2bfloat16(x0.w);
        o.h[4] = __float2bfloat16(x1.x);
        o.h[5] = __float2bfloat16(x1.y);
        o.h[6] = __float2bfloat16(x1.z);
        o.h[7] = __float2bfloat16(x1.w);
        d[i] = o.v;
    }
}

__global__ void fill_zero_kernel(uint4* __restrict__ p, int n) {
    int i = blockIdx.x * blockDim.x + threadIdx.x;
    if (i < n) p[i] = uint4{0u, 0u, 0u, 0u};
}

// out_w [100,768] -> padded bf16 [128,768] (rows 100..127 zero)
__global__ void pad_wout_kernel(const float* __restrict__ s, bf16_t* __restrict__ d) {
    int i = blockIdx.x * blockDim.x + threadIdx.x;  // exactly 128*768 threads
    int row = i / DD;
    d[i] = (row < VV) ? __float2bfloat16(s[i]) : __float2bfloat16(0.f);
}

// ---------------------------------------------------------------------------
// Embedding: x[t,:] = tok_emb[target[t],:] + pos_emb[s,:]  (writes fp32 + bf16)
// ---------------------------------------------------------------------------
__global__ void embed_kernel(const int* __restrict__ target,
                             const float* __restrict__ tok_emb,
                             const float* __restrict__ pos_emb,
                             float* __restrict__ x, bf16_t* __restrict__ xb) {
    int t = blockIdx.x;            // 0..8191
    int s = t & (SS - 1);
    int tok = target[t];
    const float* te = tok_emb + (size_t)tok * DD;
    const float* pe = pos_emb + (size_t)s * DD;
    for (int d = threadIdx.x; d < DD; d += blockDim.x) {
        float v = te[d] + pe[d];
        x[(size_t)t * DD + d] = v;
        xb[(size_t)t * DD + d] = __float2bfloat16(v);
    }
}

// ---------------------------------------------------------------------------
// Collapsed cross-attention, batched over all 16 latents per weight read.
// ---------------------------------------------------------------------------
__global__ __launch_bounds__(256) void cvmm_kernel(
    const float* __restrict__ in, int in_per_layer,
    const float* __restrict__ Wbase, size_t w_stride, size_t w_off,
    const float* __restrict__ bbase, size_t b_stride, size_t b_off,
    float* __restrict__ outp) {
    const int jc = blockIdx.x;
    const int layer = blockIdx.y;
    __shared__ float inb[BB][DD + 4];
    const int tid = threadIdx.x;
    const float* ip = in + (size_t)layer * in_per_layer;
    for (int idx = tid; idx < BB * DD; idx += 256) {
        int b = idx / DD, d = idx - b * DD;
        inb[b][d] = ip[(size_t)b * DD + d];
    }
    __syncthreads();
    const int j = jc * 16 + (tid >> 4);
    const int b = tid & 15;
    const float4* w4 = reinterpret_cast<const float4*>(
        Wbase + (size_t)layer * w_stride + w_off + (size_t)j * DD);
    const float4* i4 = reinterpret_cast<const float4*>(&inb[b][0]);
    float a = 0.f;
#pragma unroll 4
    for (int d = 0; d < DD / 4; ++d) {
        float4 w = w4[d], xv = i4[d];
        a += w.x * xv.x + w.y * xv.y + w.z * xv.z + w.w * xv.w;
    }
    a += bbase[(size_t)layer * b_stride + b_off + j];
    outp[((size_t)layer * BB + b) * DD + j] = a;
}

// ===========================================================================
// 256x256 GEMM core v3: pipelined ds_reads + COUNTED lgkmcnt.
// 512 threads = 8 waves (2M x 4N), per-wave 128x64 output, BK=64.
// LDS: A region 64 KiB (4 slots [P][half] of 256 rows x 32 cols bf16),
//      B region 64 KiB, total 128 KiB. Swizzle col^((row>>1)&3) within each
//      32-col half; reduced per-thread: sw = q ^ ((r>>1)&3) (row-indep), so
//      every ds_read is one base VGPR + compile-time immediate (zero VALU).
// v1/v2 failed at ~2275 cy/phase = serial sum of MFMA(512) + LDS-pipe(768)
// + VALU(340): every phase drained lgkmcnt to 0 before its MFMA cluster.
// v3: reads for phase p+1 are issued in phase p and stay IN FLIGHT through
// p's MFMA (counted lgkmcnt(8)/(4)); only ph3 drains to 0. The LDS pipe now
// works under the MFMA pipe -> target max(768,512)+eps per phase.
// B-frags (bb0,bb1) are read once per tile and register-held for both
// M-halves; A-frags double-buffered (aX,aY). 24 ds_read_b128/tile/wave =
// exactly one read per LDS byte (minimum possible).
// Stage schedule + vmcnt(6) discipline byte-identical to the twice-verified
// v1/v2 core (correctness unchanged; compiler auto-waitcnt is the safety
// net for the counted lgkm — a miscount costs perf, not correctness):
//   ph0: A-k1(t+1)->As[P^1][1]   ph1: B-k0(t+2)->Bs[P][0]
//   ph2: B-k1(t+2)->Bs[P][1]    ph3: A-k0(t+2)->As[P][0], then vmcnt(6)
// ===========================================================================
__device__ __forceinline__ void gemm256_core(
    const bf16_t* __restrict__ A, const bf16_t* __restrict__ W, int Kd,
    uint4* __restrict__ ASf, uint4* __restrict__ BSf,
    f32x4 (&acc)[8][4], int wave, int lane) {
    const int wr = wave >> 2, wc = wave & 3;
    const int r = lane & 15, q = lane >> 4;
    const int nt = Kd >> 6;

    // per-thread constant LDS read bases (swizzle folded in; all reads are
    // base + compile-time byte offset -> ds_read_b128 ... offset:N)
    const int sw = (q ^ ((r >> 1) & 3)) * 16;
    const char* aB = (const char*)ASf + (wr * 128 + r) * 64 + sw;
    const char* bB = (const char*)BSf + (wc * 64 + r) * 64 + sw;

    // per-thread pre-swizzled global source addresses, rnd0/rnd1 of a stage
    const int c0 = wave * 64 + lane, c1 = 512 + wave * 64 + lane;
    const int row0 = c0 >> 2, kc0 = (c0 & 3) ^ ((row0 >> 1) & 3);
    const int row1 = c1 >> 2, kc1 = (c1 & 3) ^ ((row1 >> 1) & 3);
    const bf16_t* pA0 = A + (size_t)row0 * Kd + kc0 * 8;
    const bf16_t* pA1 = A + (size_t)row1 * Kd + kc1 * 8;
    const bf16_t* pB0 = W + (size_t)row0 * Kd + kc0 * 8;
    const bf16_t* pB1 = W + (size_t)row1 * Kd + kc1 * 8;

#define GLL16(p, l)                                                            \
    __builtin_amdgcn_global_load_lds(                                          \
        (const __attribute__((address_space(1))) void*)(p),                    \
        (__attribute__((address_space(3))) void*)(l), 16, 0, 0)
// slot in {0..3} = P*2+half; koff in ELEMENTS (compile-time literal)
#define STAGE_A(slot, koff)                                                    \
    do {                                                                       \
        GLL16(pA0 + (koff), ASf + (slot)*1024 + wave * 64);                    \
        GLL16(pA1 + (koff), ASf + (slot)*1024 + 512 + wave * 64);              \
    } while (0)
#define STAGE_B(slot, koff)                                                    \
    do {                                                                       \
        GLL16(pB0 + (koff), BSf + (slot)*1024 + wave * 64);                    \
        GLL16(pB1 + (koff), BSf + (slot)*1024 + 512 + wave * 64);              \
    } while (0)
// A frag: slot (P,h), M-half mg, row-group i  (row = wr*128+mg*64+i*16+r)
#define LDA(P, h, mg, i)                                                       \
    (*(const bf16x8*)(aB + ((P)*32768 + (h)*16384 + (mg)*4096 + (i)*1024)))
#define LDB(P, h, j)                                                           \
    (*(const bf16x8*)(bB + ((P)*32768 + (h)*16384 + (j)*1024)))
#define MFMA16(MG, AF, BF)                                                     \
    _Pragma("unroll") for (int i_ = 0; i_ < 4; ++i_)                           \
    _Pragma("unroll") for (int j_ = 0; j_ < 4; ++j_)                           \
        acc[(MG)*4 + i_][j_] = __builtin_amdgcn_mfma_f32_16x16x32_bf16(        \
            AF[i_], BF[j_], acc[(MG)*4 + i_][j_], 0, 0, 0);

    // prologue: tile0 fully + tile1 B-halves + tile1 A-k0 (7 half-stages)
    STAGE_A(0, 0);     // A(0,0)  k0(t0)
    STAGE_A(1, 32);    // A(0,1)  k1(t0)
    STAGE_B(0, 0);     // B(0,0)  k0(t0)
    STAGE_B(1, 32);    // B(0,1)  k1(t0)
    STAGE_B(2, 64);    // B(1,0)  k0(t1)
    STAGE_B(3, 96);    // B(1,1)  k1(t1)
    STAGE_A(2, 64);    // A(1,0)  k0(t1)
    asm volatile("s_waitcnt vmcnt(6)" ::: "memory");  // tile0 landed
    __builtin_amdgcn_s_barrier();

    bf16x8 aX[4], aY[4], bb0[4], bb1[4];

#define TILE_V3(P, tt)                                                         \
    do {                                                                       \
        /* ph0: own reads (8) then ph1 prefetch reads (8) */                   \
        aX[0] = LDA(P, 0, 0, 0); aX[1] = LDA(P, 0, 0, 1);                      \
        aX[2] = LDA(P, 0, 0, 2); aX[3] = LDA(P, 0, 0, 3);                      \
        bb0[0] = LDB(P, 0, 0); bb0[1] = LDB(P, 0, 1);                          \
        bb0[2] = LDB(P, 0, 2); bb0[3] = LDB(P, 0, 3);                          \
        __builtin_amdgcn_sched_barrier(0); /* pin issue order for the count */ \
        aY[0] = LDA(P, 1, 0, 0); aY[1] = LDA(P, 1, 0, 1);                      \
        aY[2] = LDA(P, 1, 0, 2); aY[3] = LDA(P, 1, 0, 3);                      \
        bb1[0] = LDB(P, 1, 0); bb1[1] = LDB(P, 1, 1);                          \
        bb1[2] = LDB(P, 1, 2); bb1[3] = LDB(P, 1, 3);                          \
        asm volatile("s_waitcnt lgkmcnt(8)" ::: "memory");                     \
        __builtin_amdgcn_sched_barrier(0);                                     \
        __builtin_amdgcn_s_setprio(1);                                         \
        MFMA16(0, aX, bb0)                                                     \
        __builtin_amdgcn_s_setprio(0);                                         \
        if ((tt) + 1 < nt) STAGE_A((P ^ 1) * 2 + 1, 96);                       \
        __builtin_amdgcn_s_barrier();                                          \
        /* ph1: prefetch ph2's A (MG1,kk0); MFMA MG0 x kk1 */                  \
        aX[0] = LDA(P, 0, 1, 0); aX[1] = LDA(P, 0, 1, 1);                      \
        aX[2] = LDA(P, 0, 1, 2); aX[3] = LDA(P, 0, 1, 3);                      \
        asm volatile("s_waitcnt lgkmcnt(4)" ::: "memory");                     \
        __builtin_amdgcn_sched_barrier(0);                                     \
        __builtin_amdgcn_s_setprio(1);                                         \
        MFMA16(0, aY, bb1)                                                     \
        __builtin_amdgcn_s_setprio(0);                                         \
        if ((tt) + 2 < nt) STAGE_B((P)*2 + 0, 128);                            \
        __builtin_amdgcn_s_barrier();                                          \
        /* ph2: prefetch ph3's A (MG1,kk1); MFMA MG1 x kk0 (bb0 reg-held) */   \
        aY[0] = LDA(P, 1, 1, 0); aY[1] = LDA(P, 1, 1, 1);                      \
        aY[2] = LDA(P, 1, 1, 2); aY[3] = LDA(P, 1, 1, 3);                      \
        asm volatile("s_waitcnt lgkmcnt(4)" ::: "memory");                     \
        __builtin_amdgcn_sched_barrier(0);                                     \
        __builtin_amdgcn_s_setprio(1);                                         \
        MFMA16(1, aX, bb0)                                                     \
        __builtin_amdgcn_s_setprio(0);                                         \
        if ((tt) + 2 < nt) STAGE_B((P)*2 + 1, 160);                            \
        __builtin_amdgcn_s_barrier();                                          \
        /* ph3: MFMA MG1 x kk1; tile-boundary vmcnt publish */                 \
        asm volatile("s_waitcnt lgkmcnt(0)" ::: "memory");                     \
        __builtin_amdgcn_sched_barrier(0);                                     \
        __builtin_amdgcn_s_setprio(1);                                         \
        MFMA16(1, aY, bb1)                                                     \
        __builtin_amdgcn_s_setprio(0);                                         \
        if ((tt) + 2 < nt) {                                                   \
            STAGE_A((P)*2 + 0, 128);                                           \
            asm volatile("s_waitcnt vmcnt(6)" ::: "memory");                   \
        } else if ((tt) + 1 < nt) {                                            \
            asm volatile("s_waitcnt vmcnt(0)" ::: "memory");                   \
        }                                                                      \
        __builtin_amdgcn_s_barrier();                                          \
        pA0 += 64; pA1 += 64; pB0 += 64; pB1 += 64;                            \
    } while (0)

    for (int t = 0; t < nt; t += 2) {
        TILE_V3(0, t);
        TILE_V3(1, t + 1);
    }
#undef TILE_V3
#undef MFMA16
#undef LDB
#undef LDA
#undef STAGE_B
#undef STAGE_A
#undef GLL16
}

// 256-tile GEMM with standard epilogue (bias, optional relu/res/bf16-out).
// Grid is 1D = (M/256)*(N/256) blocks, XCD-swizzled (grid %8 == 0 required).
template <bool RELU, bool BOUT, bool RES>
__global__ __launch_bounds__(512, 2) void gemm256_bt(
    const bf16_t* __restrict__ A, const bf16_t* __restrict__ W,
    const float* __restrict__ bias, const float* __restrict__ resid,
    float* __restrict__ Cf, bf16_t* __restrict__ Cb,
    int Kd, int ldc, int nx) {
    __shared__ uint4 ASf[4096];
    __shared__ uint4 BSf[4096];
    const int nwg = gridDim.x, cpx = nwg >> 3;
    const int bid = blockIdx.x;
    const int swz = (bid & 7) * cpx + (bid >> 3);
    const int m0 = (swz / nx) * 256, n0 = (swz % nx) * 256;
    const int lane = threadIdx.x & 63, wave = threadIdx.x >> 6;
    const int wr = wave >> 2, wc = wave & 3;
    const int r = lane & 15, q = lane >> 4;

    f32x4 acc[8][4];
#pragma unroll
    for (int i = 0; i < 8; ++i)
#pragma unroll
        for (int j = 0; j < 4; ++j) acc[i][j] = f32x4{0.f, 0.f, 0.f, 0.f};

    gemm256_core(A + (size_t)m0 * Kd, W + (size_t)n0 * Kd, Kd, ASf, BSf, acc, wave, lane);

#pragma unroll
    for (int i = 0; i < 8; ++i) {
#pragma unroll
        for (int j = 0; j < 4; ++j) {
            int cc = n0 + wc * 64 + j * 16 + r;
            float bv = bias[cc];
#pragma unroll
            for (int reg = 0; reg < 4; ++reg) {
                int rr = m0 + wr * 128 + i * 16 + q * 4 + reg;
                float v = acc[i][j][reg] + bv;
                if (RES) v += resid[(size_t)rr * ldc + cc];
                if (RELU) v = fmaxf(v, 0.f);
                if (BOUT) Cb[(size_t)rr * ldc + cc] = __float2bfloat16(v);
                else Cf[(size_t)rr * ldc + cc] = v;
            }
        }
    }
}

// 256-tile QKV projection with head-scatter epilogue (same pipeline).
// Grid = 288 (9 n-tiles x 32 m-tiles), XCD-swizzled.
__global__ __launch_bounds__(512, 2) void gemm256_qkv(
    const bf16_t* __restrict__ A, const bf16_t* __restrict__ W,
    const float* __restrict__ bias,
    bf16_t* __restrict__ Qh, bf16_t* __restrict__ Kh, bf16_t* __restrict__ Vt) {
    __shared__ uint4 ASf[4096];
    __shared__ uint4 BSf[4096];
    const int nwg = gridDim.x, cpx = nwg >> 3;
    const int bid = blockIdx.x;
    const int swz = (bid & 7) * cpx + (bid >> 3);
    const int m0 = (swz / 9) * 256, n0 = (swz % 9) * 256;
    const int lane = threadIdx.x & 63, wave = threadIdx.x >> 6;
    const int wr = wave >> 2, wc = wave & 3;
    const int r = lane & 15, q = lane >> 4;

    f32x4 acc[8][4];
#pragma unroll
    for (int i = 0; i < 8; ++i)
#pragma unroll
        for (int j = 0; j < 4; ++j) acc[i][j] = f32x4{0.f, 0.f, 0.f, 0.f};

    gemm256_core(A + (size_t)m0 * DD, W + (size_t)n0 * DD, DD, ASf, BSf, acc, wave, lane);

    const float scale = 0.10206207261596575f;  // 1/sqrt(96)
#pragma unroll
    for (int i = 0; i < 8; ++i) {
#pragma unroll
        for (int j = 0; j < 4; ++j) {
            int cc = n0 + wc * 64 + j * 16 + r;   // 0..2303
            float bv = bias[cc];
            int sec = cc / DD;                    // 0=q 1=k 2=v (uniform per 16-group)
            int within = cc - sec * DD;
            int hh = within / DHH;                // uniform per 16-group (96 = 6*16)
            int dd = within - hh * DHH;
#pragma unroll
            for (int reg = 0; reg < 4; ++reg) {
                int rr = m0 + wr * 128 + i * 16 + q * 4 + reg;  // token
                float v = acc[i][j][reg] + bv;
                int b = rr >> 9, s = rr & 511;
                int bh = b * HH + hh;
                if (sec == 0)
                    Qh[((size_t)bh * SS + s) * 128 + dd] = __float2bfloat16(v * scale);
                else if (sec == 1)
                    Kh[((size_t)bh * SS + s) * 128 + dd] = __float2bfloat16(v);
                else
                    Vt[((size_t)bh * 128 + dd) * SS + s] = __float2bfloat16(v);
            }
        }
    }
}

// ---------------------------------------------------------------------------
// bf16 MFMA GEMM: C[M,N] = A[M,K] @ W[N,K]^T + bias (+resid) (+relu)
// 128x128 tile, BK=64, 256 threads = 4 waves, each wave 64x64 (4x4 mfma tiles).
// Kept for o-proj / ffn2 / logits (and as fallback).
// ---------------------------------------------------------------------------
template <bool RELU, bool BOUT, bool RES>
__global__ __launch_bounds__(256, 3) void gemm_bt(
    const bf16_t* __restrict__ A, const bf16_t* __restrict__ W,
    const float* __restrict__ bias, const float* __restrict__ resid,
    float* __restrict__ Cf, bf16_t* __restrict__ Cb,
    int K, int ldc, int Nreal) {
    __shared__ uint4 As4[128 * 8];
    __shared__ uint4 Bs4[128 * 8];
    const int m0 = blockIdx.y * 128;
    const int n0 = blockIdx.x * 128;
    const int lane = threadIdx.x & 63, wave = threadIdx.x >> 6;
    const int wr = wave >> 1, wc = wave & 1;
    const int r = lane & 15, q = lane >> 4;

    f32x4 acc[4][4];
#pragma unroll
    for (int i = 0; i < 4; ++i)
#pragma unroll
        for (int j = 0; j < 4; ++j) acc[i][j] = f32x4{0.f, 0.f, 0.f, 0.f};

    for (int k0 = 0; k0 < K; k0 += 64) {
#pragma unroll
        for (int it = 0; it < 4; ++it) {
            int base = it * 256 + wave * 64;  // wave-uniform LDS chunk base
            int c = base + lane;
            int row = c >> 3, pc = c & 7;
            int kc = pc ^ (row & 7);
            load_lds16(A + (size_t)(m0 + row) * K + k0 + kc * 8, &As4[base]);
            load_lds16(W + (size_t)(n0 + row) * K + k0 + kc * 8, &Bs4[base]);
        }
        __syncthreads();
#pragma unroll
        for (int kk = 0; kk < 2; ++kk) {
            bf16x8 af[4], bfr[4];
            int lc = kk * 4 + q;
#pragma unroll
            for (int i = 0; i < 4; ++i) {
                int rowA = wr * 64 + i * 16 + r;
                af[i] = *reinterpret_cast<const bf16x8*>(&As4[rowA * 8 + (lc ^ (rowA & 7))]);
                int rowB = wc * 64 + i * 16 + r;
                bfr[i] = *reinterpret_cast<const bf16x8*>(&Bs4[rowB * 8 + (lc ^ (rowB & 7))]);
            }
#pragma unroll
            for (int i = 0; i < 4; ++i)
#pragma unroll
                for (int j = 0; j < 4; ++j)
                    acc[i][j] = __builtin_amdgcn_mfma_f32_16x16x32_bf16(af[i], bfr[j], acc[i][j], 0, 0, 0);
        }
        __syncthreads();
    }

#pragma unroll
    for (int i = 0; i < 4; ++i) {
#pragma unroll
        for (int j = 0; j < 4; ++j) {
            int cc = n0 + wc * 64 + j * 16 + r;
            if (cc < Nreal) {
                float bv = bias[cc];
#pragma unroll
                for (int reg = 0; reg < 4; ++reg) {
                    int rr = m0 + wr * 64 + i * 16 + q * 4 + reg;
                    float v = acc[i][j][reg] + bv;
                    if (RES) v += resid[(size_t)rr * ldc + cc];
                    if (RELU) v = fmaxf(v, 0.f);
                    if (BOUT) Cb[(size_t)rr * ldc + cc] = __float2bfloat16(v);
                    else Cf[(size_t)rr * ldc + cc] = v;
                }
            }
        }
    }
}

// ---------------------------------------------------------------------------
// Batched score GEMM: Sc[bh] = Qh[bh] @ Kh[bh]^T   (scale folded into Q)
// M=N=512, K=128 (zero-padded head dim). Skips upper-triangle tiles.
// ---------------------------------------------------------------------------
__global__ __launch_bounds__(256, 3) void gemm_sc(
    const bf16_t* __restrict__ Qh, const bf16_t* __restrict__ Kh,
    bf16_t* __restrict__ Scb) {
    const int bh = blockIdx.z;
    const int m0 = blockIdx.y * 128;
    const int n0 = blockIdx.x * 128;
    if (n0 > m0) return;  // fully above the causal diagonal
    const bf16_t* A = Qh + (size_t)bh * SS * 128;
    const bf16_t* W = Kh + (size_t)bh * SS * 128;
    __shared__ uint4 As4[128 * 8];
    __shared__ uint4 Bs4[128 * 8];
    const int lane = threadIdx.x & 63, wave = threadIdx.x >> 6;
    const int wr = wave >> 1, wc = wave & 1;
    const int r = lane & 15, q = lane >> 4;
    const int K = 128;

    f32x4 acc[4][4];
#pragma unroll
    for (int i = 0; i < 4; ++i)
#pragma unroll
        for (int j = 0; j < 4; ++j) acc[i][j] = f32x4{0.f, 0.f, 0.f, 0.f};

    for (int k0 = 0; k0 < K; k0 += 64) {
#pragma unroll
        for (int it = 0; it < 4; ++it) {
            int base = it * 256 + wave * 64;
            int c = base + lane;
            int row = c >> 3, pc = c & 7;
            int kc = pc ^ (row & 7);
            load_lds16(A + (size_t)(m0 + row) * K + k0 + kc * 8, &As4[base]);
            load_lds16(W + (size_t)(n0 + row) * K + k0 + kc * 8, &Bs4[base]);
        }
        __syncthreads();
#pragma unroll
        for (int kk = 0; kk < 2; ++kk) {
            bf16x8 af[4], bfr[4];
            int lc = kk * 4 + q;
#pragma unroll
            for (int i = 0; i < 4; ++i) {
                int rowA = wr * 64 + i * 16 + r;
                af[i] = *reinterpret_cast<const bf16x8*>(&As4[rowA * 8 + (lc ^ (rowA & 7))]);
                int rowB = wc * 64 + i * 16 + r;
                bfr[i] = *reinterpret_cast<const bf16x8*>(&Bs4[rowB * 8 + (lc ^ (rowB & 7))]);
            }
#pragma unroll
            for (int i = 0; i < 4; ++i)
#pragma unroll
                for (int j = 0; j < 4; ++j)
                    acc[i][j] = __builtin_amdgcn_mfma_f32_16x16x32_bf16(af[i], bfr[j], acc[i][j], 0, 0, 0);
        }
        __syncthreads();
    }

    bf16_t* out = Scb + (size_t)bh * SS * SS;
#pragma unroll
    for (int i = 0; i < 4; ++i) {
#pragma unroll
        for (int j = 0; j < 4; ++j) {
            int cc = n0 + wc * 64 + j * 16 + r;
#pragma unroll
            for (int reg = 0; reg < 4; ++reg) {
                int rr = m0 + wr * 64 + i * 16 + q * 4 + reg;
                out[(size_t)rr * SS + cc] = __float2bfloat16(acc[i][j][reg]);
            }
        }
    }
}

// ---------------------------------------------------------------------------
// Causal softmax in place over bf16 scores. One wave per row of 512.
// Only [0, kend) is processed, where kend = end of this row's q-tile:
// gemm_pv never reads kv >= kend (its K-loop stops at m0+128 == kend for
// every row in the tile). Zeros are still written for [kn, kend).
// ---------------------------------------------------------------------------
__global__ __launch_bounds__(256) void softmax_kernel(bf16_t* __restrict__ Scb) {
    const int wave = threadIdx.x >> 6, lane = threadIdx.x & 63;
    const int row = blockIdx.x * 4 + wave;   // bh*512 + q
    const int qpos = row & (SS - 1);
    const int kn = qpos + 1;
    const int kend = ((qpos >> 7) + 1) << 7;  // 128/256/384/512 (wave-uniform)
    const bool act = (lane << 3) < kend;
    bf16_t* rp = Scb + (size_t)row * SS;
    union {
        uint4 v;
        bf16_t h[8];
    } u;
    float vals[8];
    float m = -1e30f;
    if (act) {
        u.v = *reinterpret_cast<const uint4*>(rp + lane * 8);
#pragma unroll
        for (int e = 0; e < 8; ++e) {
            int j = lane * 8 + e;
            vals[e] = (j < kn) ? __bfloat162float(u.h[e]) : -1e30f;
            m = fmaxf(m, vals[e]);
        }
    } else {
#pragma unroll
        for (int e = 0; e < 8; ++e) vals[e] = -1e30f;
    }
#pragma unroll
    for (int s = 1; s < 64; s <<= 1) m = fmaxf(m, __shfl_xor(m, s));
    float sum = 0.f;
#pragma unroll
    for (int e = 0; e < 8; ++e) {
        vals[e] = __expf(vals[e] - m);
        sum += vals[e];
    }
#pragma unroll
    for (int s = 1; s < 64; s <<= 1) sum += __shfl_xor(sum, s);
    const float inv = 1.f / sum;
    if (act) {
#pragma unroll
        for (int e = 0; e < 8; ++e) u.h[e] = __float2bfloat16(vals[e] * inv);
        *reinterpret_cast<uint4*>(rp + lane * 8) = u.v;
    }
}

// ---------------------------------------------------------------------------
// Batched P@V GEMM: ao[bh rows] = P[bh] @ Vt[bh]^T, causal K-limit:
// P[:, k >= m0+128] is exactly zero for rows in tile m0 -> K-loop to m0+128.
// N tile = 128 (cols 96..127 garbage, guarded). Writes ao [T,768] bf16.
// ---------------------------------------------------------------------------
__global__ __launch_bounds__(256, 3) void gemm_pv(
    const bf16_t* __restrict__ P, const bf16_t* __restrict__ Vt,
    bf16_t* __restrict__ ao) {
    const int bh = blockIdx.z;
    const int m0 = blockIdx.y * 128;
    const bf16_t* A = P + (size_t)bh * SS * SS;
    const bf16_t* W = Vt + (size_t)bh * 128 * SS;
    __shared__ uint4 As4[128 * 8];
    __shared__ uint4 Bs4[128 * 8];
    const int lane = threadIdx.x & 63, wave = threadIdx.x >> 6;
    const int wr = wave >> 1, wc = wave & 1;
    const int r = lane & 15, q = lane >> 4;
    const int K = SS;         // row stride of P / Vt
    const int kmax = m0 + 128;  // causal: P zero beyond this for all tile rows

    f32x4 acc[4][4];
#pragma unroll
    for (int i = 0; i < 4; ++i)
#pragma unroll
        for (int j = 0; j < 4; ++j) acc[i][j] = f32x4{0.f, 0.f, 0.f, 0.f};

    for (int k0 = 0; k0 < kmax; k0 += 64) {
#pragma unroll
        for (int it = 0; it < 4; ++it) {
            int base = it * 256 + wave * 64;
            int c = base + lane;
            int row = c >> 3, pc = c & 7;
            int kc = pc ^ (row & 7);
            load_lds16(A + (size_t)(m0 + row) * K + k0 + kc * 8, &As4[base]);
            load_lds16(W + (size_t)row * K + k0 + kc * 8, &Bs4[base]);
        }
        __syncthreads();
#pragma unroll
        for (int kk = 0; kk < 2; ++kk) {
            bf16x8 af[4], bfr[4];
            int lc = kk * 4 + q;
#pragma unroll
            for (int i = 0; i < 4; ++i) {
                int rowA = wr * 64 + i * 16 + r;
                af[i] = *reinterpret_cast<const bf16x8*>(&As4[rowA * 8 + (lc ^ (rowA & 7))]);
                int rowB = wc * 64 + i * 16 + r;
                bfr[i] = *reinterpret_cast<const bf16x8*>(&Bs4[rowB * 8 + (lc ^ (rowB & 7))]);
            }
#pragma unroll
            for (int i = 0; i < 4; ++i)
#pragma unroll
                for (int j = 0; j < 4; ++j)
                    acc[i][j] = __builtin_amdgcn_mfma_f32_16x16x32_bf16(af[i], bfr[j], acc[i][j], 0, 0, 0);
        }
        __syncthreads();
    }

    const int b = bh >> 3, hh = bh & 7;
#pragma unroll
    for (int i = 0; i < 4; ++i) {
#pragma unroll
        for (int j = 0; j < 4; ++j) {
            int cc = wc * 64 + j * 16 + r;  // head dim 0..127
            if (cc < DHH) {
#pragma unroll
                for (int reg = 0; reg < 4; ++reg) {
                    int s = m0 + wr * 64 + i * 16 + q * 4 + reg;
                    size_t t = (size_t)b * SS + s;
                    ao[t * DD + hh * DHH + cc] = __float2bfloat16(acc[i][j][reg]);
                }
            }
        }
    }
}

// ---------------------------------------------------------------------------
// LayerNorm over D=768. In-place safe.
// ---------------------------------------------------------------------------
__global__ __launch_bounds__(256) void ln_kernel(const float* __restrict__ in,
                                                 const float* __restrict__ g,
                                                 const float* __restrict__ beta,
                                                 float* __restrict__ xo,
                                                 bf16_t* __restrict__ xb) {
    const int row = blockIdx.x;
    const int tid = threadIdx.x;
    const float* ip = in + (size_t)row * DD;
    float v[3];
#pragma unroll
    for (int t = 0; t < 3; ++t) v[t] = ip[tid + t * 256];
    float s = v[0] + v[1] + v[2];
    float ss = v[0] * v[0] + v[1] * v[1] + v[2] * v[2];
    for (int off = 32; off > 0; off >>= 1) {
        s += __shfl_down(s, off);
        ss += __shfl_down(ss, off);
    }
    __shared__ float red[8];
    if ((tid & 63) == 0) {
        red[(tid >> 6) * 2] = s;
        red[(tid >> 6) * 2 + 1] = ss;
    }
    __syncthreads();
    s = red[0] + red[2] + red[4] + red[6];
    ss = red[1] + red[3] + red[5] + red[7];
    const float mean = s * (1.f / DD);
    const float var = ss * (1.f / DD) - mean * mean;
    const float rs = rsqrtf(var + 1e-5f);
#pragma unroll
    for (int t = 0; t < 3; ++t) {
        int d = tid + t * 256;
        float y = (v[t] - mean) * rs * g[d] + beta[d];
        xo[(size_t)row * DD + d] = y;
        xb[(size_t)row * DD + d] = __float2bfloat16(y);
    }
}

// ---------------------------------------------------------------------------
// Fused LN1 -> +cv broadcast -> LN2. Reads tmp once, writes x + xb once.
// ---------------------------------------------------------------------------
__global__ __launch_bounds__(256) void ln12_kernel(const float* __restrict__ in,
                                                   const float* __restrict__ cvv,
                                                   const float* __restrict__ g1,
                                                   const float* __restrict__ b1,
                                                   const float* __restrict__ g2,
                                                   const float* __restrict__ b2,
                                                   float* __restrict__ xo,
                                                   bf16_t* __restrict__ xb) {
    const int row = blockIdx.x;
    const int tid = threadIdx.x;
    const float* ip = in + (size_t)row * DD;
    const float* cp = cvv + (size_t)(row >> 9) * DD;
    __shared__ float red[8];
    float v[3];
#pragma unroll
    for (int t = 0; t < 3; ++t) v[t] = ip[tid + t * 256];
    // ---- LN1
    float s = v[0] + v[1] + v[2];
    float ss = v[0] * v[0] + v[1] * v[1] + v[2] * v[2];
    for (int off = 32; off > 0; off >>= 1) {
        s += __shfl_down(s, off);
        ss += __shfl_down(ss, off);
    }
    if ((tid & 63) == 0) {
        red[(tid >> 6) * 2] = s;
        red[(tid >> 6) * 2 + 1] = ss;
    }
    __syncthreads();
    s = red[0] + red[2] + red[4] + red[6];
    ss = red[1] + red[3] + red[5] + red[7];
    float mean = s * (1.f / DD);
    float var = ss * (1.f / DD) - mean * mean;
    float rs = rsqrtf(var + 1e-5f);
#pragma unroll
    for (int t = 0; t < 3; ++t) {
        int d = tid + t * 256;
        v[t] = (v[t] - mean) * rs * g1[d] + b1[d] + cp[d];
    }
    // ---- LN2
    s = v[0] + v[1] + v[2];
    ss = v[0] * v[0] + v[1] * v[1] + v[2] * v[2];
    for (int off = 32; off > 0; off >>= 1) {
        s += __shfl_down(s, off);
        ss += __shfl_down(ss, off);
    }
    __syncthreads();  // protect red reuse
    if ((tid & 63) == 0) {
        red[(tid >> 6) * 2] = s;
        red[(tid >> 6) * 2 + 1] = ss;
    }
    __syncthreads();
    s = red[0] + red[2] + red[4] + red[6];
    ss = red[1] + red[3] + red[5] + red[7];
    mean = s * (1.f / DD);
    var = ss * (1.f / DD) - mean * mean;
    rs = rsqrtf(var + 1e-5f);
#pragma unroll
    for (int t = 0; t < 3; ++t) {
        int d = tid + t * 256;
        float y = (v[t] - mean) * rs * g2[d] + b2[d];
        xo[(size_t)row * DD + d] = y;
        xb[(size_t)row * DD + d] = __float2bfloat16(y);
    }
}

// ---------------------------------------------------------------------------
// Host launcher
// ---------------------------------------------------------------------------
extern "C" void kernel_launch(void* const* d_in, const int* in_sizes, int n_in,
                              void* d_out, int out_size, void* d_ws, size_t ws_size,
                              hipStream_t stream) {
    (void)in_sizes; (void)n_in; (void)out_size; (void)ws_size;
    const float* latent   = (const float*)d_in[0];
    const int*   target   = (const int*)d_in[1];
    const float* tok_emb  = (const float*)d_in[2];
    const float* pos_emb  = (const float*)d_in[3];
    const float* sa_w_qkv = (const float*)d_in[4];
    const float* sa_b_qkv = (const float*)d_in[5];
    const float* sa_w_o   = (const float*)d_in[6];
    const float* sa_b_o   = (const float*)d_in[7];
    const float* ca_w_qkv = (const float*)d_in[8];
    const float* ca_b_qkv = (const float*)d_in[9];
    const float* ca_w_o   = (const float*)d_in[10];
    const float* ca_b_o   = (const float*)d_in[11];
    const float* ffn_w1   = (const float*)d_in[12];
    const float* ffn_b1   = (const float*)d_in[13];
    const float* ffn_w2   = (const float*)d_in[14];
    const float* ffn_b2   = (const float*)d_in[15];
    const float* ln1_g    = (const float*)d_in[16];
    const float* ln1_b    = (const float*)d_in[17];
    const float* ln2_g    = (const float*)d_in[18];
    const float* ln2_b    = (const float*)d_in[19];
    const float* ln3_g    = (const float*)d_in[20];
    const float* ln3_b    = (const float*)d_in[21];
    const float* out_w    = (const float*)d_in[22];
    const float* out_b    = (const float*)d_in[23];
    float* out = (float*)d_out;

    // workspace carve-up (256B aligned)
    char* ws = (char*)d_ws;
    size_t off = 0;
    auto alloc = [&](size_t bytes) {
        void* p = ws + off;
        off += (bytes + 255) & ~(size_t)255;
        return p;
    };
    float*  x    = (float*)alloc((size_t)TT * DD * 4);        // residual stream fp32
    bf16_t* xb   = (bf16_t*)alloc((size_t)TT * DD * 2);       // bf16 shadow
    bf16_t* ao   = (bf16_t*)alloc((size_t)TT * DD * 2);       // attn out bf16
    float*  cv   = (float*)alloc((size_t)LL * BB * DD * 4);   // cross-attn vectors
    float*  v16  = (float*)alloc((size_t)LL * BB * DD * 4);   // cv stage-1 temp
    bf16_t* wqkv_b = (bf16_t*)alloc((size_t)LL * 3 * DD * DD * 2);
    bf16_t* wo_b   = (bf16_t*)alloc((size_t)LL * DD * DD * 2);
    bf16_t* w1_b   = (bf16_t*)alloc((size_t)LL * FF * DD * 2);
    bf16_t* w2_b   = (bf16_t*)alloc((size_t)LL * DD * FF * 2);
    bf16_t* wout_b = (bf16_t*)alloc((size_t)128 * DD * 2);
    // Attention region:
    //   Qh [128][512][128] bf16 (16.78 MB)  zero-padded cols 96..127 (filled once)
    //   Kh [128][512][128] bf16 (16.78 MB)  zero-padded cols 96..127 (filled once)
    //   Vt [128][128][512] bf16 (16.78 MB)  rows 96..127 unused garbage (guarded)
    //   Scb[128][512][512] bf16 (67.1 MB)   scores, then P in place
    char* attnR = (char*)alloc((size_t)BH * SS * 128 * 2 * 3 + (size_t)BH * SS * SS * 2);
    bf16_t* Qh  = (bf16_t*)attnR;
    bf16_t* Kh  = Qh + (size_t)BH * SS * 128;
    bf16_t* Vt  = Kh + (size_t)BH * SS * 128;
    bf16_t* Scb = Vt + (size_t)BH * 128 * SS;
    // FFN-phase overlays go inside Scb ONLY (67.1 MB >= 33.6 + 25.2 MB).
    bf16_t* h   = Scb;                                         // [T,2048] bf16 (33.6 MB)
    float*  tmp = (float*)((char*)Scb + ((size_t)34 << 20));   // [T,768] fp32 (25.2 MB)

    // weight conversions (every call: ws is re-poisoned)
    cvt8_kernel<<<2048, 256, 0, stream>>>((const float4*)sa_w_qkv, (uint4*)wqkv_b, LL * 3 * DD * DD / 8);
    cvt8_kernel<<<2048, 256, 0, stream>>>((const float4*)sa_w_o, (uint4*)wo_b, LL * DD * DD / 8);
    cvt8_kernel<<<2048, 256, 0, stream>>>((const float4*)ffn_w1, (uint4*)w1_b, LL * FF * DD / 8);
    cvt8_kernel<<<2048, 256, 0, stream>>>((const float4*)ffn_w2, (uint4*)w2_b, LL * DD * FF / 8);
    pad_wout_kernel<<<(128 * DD) / 256, 256, 0, stream>>>(out_w, wout_b);
    // zero Qh+Kh (pad columns 96..127 must be 0; zero both fully, once per call)
    {
        int n4 = (int)(((size_t)BH * SS * 128 * 2 * 2) / 16);  // uint4 count
        fill_zero_kernel<<<(n4 + 255) / 256, 256, 0, stream>>>((uint4*)Qh, n4);
    }

    // collapsed cross-attention: v16 = latent @ Wv^T + bv; cv = v16 @ Wo^T + bo
    cvmm_kernel<<<dim3(DD / 16, LL), 256, 0, stream>>>(
        latent, 0, ca_w_qkv, (size_t)3 * DD * DD, (size_t)2 * DD * DD,
        ca_b_qkv, (size_t)3 * DD, (size_t)2 * DD, v16);
    cvmm_kernel<<<dim3(DD / 16, LL), 256, 0, stream>>>(
        v16, BB * DD, ca_w_o, (size_t)DD * DD, 0,
        ca_b_o, (size_t)DD, 0, cv);

    // embeddings
    embed_kernel<<<TT, 256, 0, stream>>>(target, tok_emb, pos_emb, x, xb);

    for (int i = 0; i < LL; ++i) {
        // QKV projection -> Qh/Kh/Vt (head-major bf16, scale folded into Q)
        // 256x256 pipelined-read kernel: grid 9*32=288, 512 threads
        gemm256_qkv<<<dim3(288), 512, 0, stream>>>(
            xb, wqkv_b + (size_t)i * 3 * DD * DD, sa_b_qkv + (size_t)i * 3 * DD,
            Qh, Kh, Vt);
        // scores (lower-triangle tiles only)
        gemm_sc<<<dim3(4, 4, BH), 256, 0, stream>>>(Qh, Kh, Scb);
        // causal softmax in place -> P (bf16, zeros up to q-tile boundary)
        softmax_kernel<<<(BH * SS) / 4, 256, 0, stream>>>(Scb);
        // P @ V -> ao (causal K-limit)
        gemm_pv<<<dim3(1, 4, BH), 256, 0, stream>>>(Scb, Vt, ao);
        // O projection + residual -> tmp
        gemm_bt<false, false, true><<<dim3(DD / 128, TT / 128), 256, 0, stream>>>(
            ao, wo_b + (size_t)i * DD * DD, sa_b_o + (size_t)i * DD,
            x, tmp, nullptr, DD, DD, DD);
        // LN1 + cv + LN2 fused -> x, xb
        ln12_kernel<<<TT, 256, 0, stream>>>(tmp, cv + (size_t)i * BB * DD,
                                            ln1_g + (size_t)i * DD, ln1_b + (size_t)i * DD,
                                            ln2_g + (size_t)i * DD, ln2_b + (size_t)i * DD,
                                            x, xb);
        // FFN1: relu(x@W1^T+b1) -> h (bf16), 256x256 pipelined: grid 8*32=256
        gemm256_bt<true, true, false><<<dim3(256), 512, 0, stream>>>(
            xb, w1_b + (size_t)i * FF * DD, ffn_b1 + (size_t)i * FF,
            nullptr, nullptr, h, DD, FF, 8);
        // FFN2 + residual -> tmp
        gemm_bt<false, false, true><<<dim3(DD / 128, TT / 128), 256, 0, stream>>>(
            h, w2_b + (size_t)i * DD * FF, ffn_b2 + (size_t)i * DD,
            x, tmp, nullptr, FF, DD, DD);
        // LN3 -> x, xb
        ln_kernel<<<TT, 256, 0, stream>>>(tmp, ln3_g + (size_t)i * DD,
                                          ln3_b + (size_t)i * DD, x, xb);
    }

    // final projection to logits [8192,100] (padded N=128, guarded)
    gemm_bt<false, false, false><<<dim3(1, TT / 128), 256, 0, stream>>>(
        xb, wout_b, out_b, nullptr, out, nullptr, DD, VV, VV);
}

// Round 4
// 1891.270 us; speedup vs baseline: 1.0419x; 1.0419x over previous
//
#include <hip/hip_runtime.h>
#include <hip/hip_bf16.h>

// Problem constants
#define BB 16
#define SS 512
#define DD 768
#define HH 8
#define VV 100
#define FF 2048
#define LL 6
#define DHH 96
#define TT (BB * SS)  // 8192 token rows
#define BH (BB * HH)  // 128 (batch,head) pairs

typedef __bf16 bf16x8 __attribute__((ext_vector_type(8)));
typedef float f32x4 __attribute__((ext_vector_type(4)));
typedef __hip_bfloat16 bf16_t;

// async global->LDS, 16B per lane; deposit = wave-uniform lds base + lane*16
__device__ __forceinline__ void load_lds16(const void* g, void* l) {
    __builtin_amdgcn_global_load_lds(
        (const __attribute__((address_space(1))) void*)g,
        (__attribute__((address_space(3))) void*)l, 16, 0, 0);
}

// ---------------------------------------------------------------------------
// fp32 -> bf16 conversion, 8 elements/thread (all sizes are %8==0)
// ---------------------------------------------------------------------------
__global__ void cvt8_kernel(const float4* __restrict__ s, uint4* __restrict__ d, int n8) {
    int i = blockIdx.x * blockDim.x + threadIdx.x;
    int stride = gridDim.x * blockDim.x;
    for (; i < n8; i += stride) {
        float4 x0 = s[2 * i], x1 = s[2 * i + 1];
        union { uint4 v; bf16_t h[8]; } o;
        o.h[0] = __float2bfloat16(x0.x);
        o.h[1] = __float2bfloat16(x0.y);
        o.h[2] = __float2bfloat16(x0.z);
        o.h[3] = __float2bfloat16(x0.w);
        o.h[4] = __float2bfloat16(x1.x);
        o.h[5] = __float2bfloat16(x1.y);
        o.h[6] = __float2bfloat16(x1.z);
        o.h[7] = __float2bfloat16(x1.w);
        d[i] = o.v;
    }
}

__global__ void fill_zero_kernel(uint4* __restrict__ p, int n) {
    int i = blockIdx.x * blockDim.x + threadIdx.x;
    if (i < n) p[i] = uint4{0u, 0u, 0u, 0u};
}

// Re-zero the pad columns (dd 96..127) of Qh and Kh. Needed per layer
// because ffn1's h-overlay (h lives in the Qh+Kh region) trashes them.
// 2 buffers x 65536 rows x 4 uint4-chunks = 524288 threads.
__global__ __launch_bounds__(256) void zero_pads_kernel(bf16_t* __restrict__ Qh,
                                                        bf16_t* __restrict__ Kh) {
    int i = blockIdx.x * blockDim.x + threadIdx.x;
    int which = i >> 18;            // 262144 = 128*512*4
    int rem = i & 262143;
    int rs = rem >> 2;              // bh*512 + s
    int c = rem & 3;                // 4 x 16B chunks = 32 bf16 cols
    bf16_t* base = which ? Kh : Qh;
    uint4* p = (uint4*)(base + (size_t)rs * 128 + 96);
    p[c] = uint4{0u, 0u, 0u, 0u};
}

// out_w [100,768] -> padded bf16 [128,768] (rows 100..127 zero)
__global__ void pad_wout_kernel(const float* __restrict__ s, bf16_t* __restrict__ d) {
    int i = blockIdx.x * blockDim.x + threadIdx.x;  // exactly 128*768 threads
    int row = i / DD;
    d[i] = (row < VV) ? __float2bfloat16(s[i]) : __float2bfloat16(0.f);
}

// ---------------------------------------------------------------------------
// Embedding: x[t,:] = tok_emb[target[t],:] + pos_emb[s,:]  (writes fp32 + bf16)
// ---------------------------------------------------------------------------
__global__ void embed_kernel(const int* __restrict__ target,
                             const float* __restrict__ tok_emb,
                             const float* __restrict__ pos_emb,
                             float* __restrict__ x, bf16_t* __restrict__ xb) {
    int t = blockIdx.x;            // 0..8191
    int s = t & (SS - 1);
    int tok = target[t];
    const float* te = tok_emb + (size_t)tok * DD;
    const float* pe = pos_emb + (size_t)s * DD;
    for (int d = threadIdx.x; d < DD; d += blockDim.x) {
        float v = te[d] + pe[d];
        x[(size_t)t * DD + d] = v;
        xb[(size_t)t * DD + d] = __float2bfloat16(v);
    }
}

// ---------------------------------------------------------------------------
// Collapsed cross-attention, batched over all 16 latents per weight read.
// ---------------------------------------------------------------------------
__global__ __launch_bounds__(256) void cvmm_kernel(
    const float* __restrict__ in, int in_per_layer,
    const float* __restrict__ Wbase, size_t w_stride, size_t w_off,
    const float* __restrict__ bbase, size_t b_stride, size_t b_off,
    float* __restrict__ outp) {
    const int jc = blockIdx.x;
    const int layer = blockIdx.y;
    __shared__ float inb[BB][DD + 4];
    const int tid = threadIdx.x;
    const float* ip = in + (size_t)layer * in_per_layer;
    for (int idx = tid; idx < BB * DD; idx += 256) {
        int b = idx / DD, d = idx - b * DD;
        inb[b][d] = ip[(size_t)b * DD + d];
    }
    __syncthreads();
    const int j = jc * 16 + (tid >> 4);
    const int b = tid & 15;
    const float4* w4 = reinterpret_cast<const float4*>(
        Wbase + (size_t)layer * w_stride + w_off + (size_t)j * DD);
    const float4* i4 = reinterpret_cast<const float4*>(&inb[b][0]);
    float a = 0.f;
#pragma unroll 4
    for (int d = 0; d < DD / 4; ++d) {
        float4 w = w4[d], xv = i4[d];
        a += w.x * xv.x + w.y * xv.y + w.z * xv.z + w.w * xv.w;
    }
    a += bbase[(size_t)layer * b_stride + b_off + j];
    outp[((size_t)layer * BB + b) * DD + j] = a;
}

// ---------------------------------------------------------------------------
// bf16 MFMA GEMM: C[M,N] = A[M,K] @ W[N,K]^T + bias (+resid) (+relu)
// 128x128 tile, BK=64, 256 threads = 4 waves, each wave 64x64 (4x4 mfma tiles).
// PROVEN structure (round-0, 62 us qkv). This round adds, without touching
// the inner loop:
//  - 1D grid + bijective XCD swizzle (T1): consecutive same-XCD blocks share
//    the A panel -> L2 hits instead of HBM re-fetch (round-0 FETCH was 70 MB
//    vs ~16 ideal). All grids are %8 == 0.
//  - optional split-K via gridDim.z: z=0 -> Cf with bias(+resid), z=1 -> bare
//    partial into Cf2. Used for the N=768 GEMMs (o-proj, ffn2) whose 384-block
//    grids left half the CUs idle; 768 blocks = exactly 3 blocks/CU.
// ---------------------------------------------------------------------------
template <bool RELU, bool BOUT, bool RES>
__global__ __launch_bounds__(256, 3) void gemm_bt(
    const bf16_t* __restrict__ A, const bf16_t* __restrict__ W,
    const float* __restrict__ bias, const float* __restrict__ resid,
    float* __restrict__ Cf, bf16_t* __restrict__ Cb, float* __restrict__ Cf2,
    int K, int Ks, int ldc, int Nreal, int nx) {
    __shared__ uint4 As4[128 * 8];
    __shared__ uint4 Bs4[128 * 8];
    const int nwg = gridDim.x, cpx = nwg >> 3;
    const int swz = (blockIdx.x & 7) * cpx + (blockIdx.x >> 3);
    const int m0 = (swz / nx) * 128;
    const int n0 = (swz % nx) * 128;
    const int z = blockIdx.z;
    const int kbeg = z * Ks, kend = kbeg + Ks;
    const int lane = threadIdx.x & 63, wave = threadIdx.x >> 6;
    const int wr = wave >> 1, wc = wave & 1;
    const int r = lane & 15, q = lane >> 4;

    f32x4 acc[4][4];
#pragma unroll
    for (int i = 0; i < 4; ++i)
#pragma unroll
        for (int j = 0; j < 4; ++j) acc[i][j] = f32x4{0.f, 0.f, 0.f, 0.f};

    for (int k0 = kbeg; k0 < kend; k0 += 64) {
#pragma unroll
        for (int it = 0; it < 4; ++it) {
            int base = it * 256 + wave * 64;  // wave-uniform LDS chunk base
            int c = base + lane;
            int row = c >> 3, pc = c & 7;
            int kc = pc ^ (row & 7);
            load_lds16(A + (size_t)(m0 + row) * K + k0 + kc * 8, &As4[base]);
            load_lds16(W + (size_t)(n0 + row) * K + k0 + kc * 8, &Bs4[base]);
        }
        __syncthreads();
#pragma unroll
        for (int kk = 0; kk < 2; ++kk) {
            bf16x8 af[4], bfr[4];
            int lc = kk * 4 + q;
#pragma unroll
            for (int i = 0; i < 4; ++i) {
                int rowA = wr * 64 + i * 16 + r;
                af[i] = *reinterpret_cast<const bf16x8*>(&As4[rowA * 8 + (lc ^ (rowA & 7))]);
                int rowB = wc * 64 + i * 16 + r;
                bfr[i] = *reinterpret_cast<const bf16x8*>(&Bs4[rowB * 8 + (lc ^ (rowB & 7))]);
            }
#pragma unroll
            for (int i = 0; i < 4; ++i)
#pragma unroll
                for (int j = 0; j < 4; ++j)
                    acc[i][j] = __builtin_amdgcn_mfma_f32_16x16x32_bf16(af[i], bfr[j], acc[i][j], 0, 0, 0);
        }
        __syncthreads();
    }

    float* Co = (z == 0) ? Cf : Cf2;
#pragma unroll
    for (int i = 0; i < 4; ++i) {
#pragma unroll
        for (int j = 0; j < 4; ++j) {
            int cc = n0 + wc * 64 + j * 16 + r;
            if (cc < Nreal) {
                float bv = (z == 0) ? bias[cc] : 0.f;
#pragma unroll
                for (int reg = 0; reg < 4; ++reg) {
                    int rr = m0 + wr * 64 + i * 16 + q * 4 + reg;
                    float v = acc[i][j][reg] + bv;
                    if (RES && z == 0) v += resid[(size_t)rr * ldc + cc];
                    if (RELU) v = fmaxf(v, 0.f);
                    if (BOUT) Cb[(size_t)rr * ldc + cc] = __float2bfloat16(v);
                    else Co[(size_t)rr * ldc + cc] = v;
                }
            }
        }
    }
}

// ---------------------------------------------------------------------------
// QKV projection GEMM with head-scatter epilogue (proven round-0 structure +
// XCD swizzle). Grid 1D = 1152 (nx = 18 n-tiles, 64 m-tiles).
// Writes: Qh [bh][512][128] bf16 (scaled by 1/sqrt(96), cols 96..127 pre-zeroed)
//         Kh [bh][512][128] bf16
//         Vt [bh][128][512] bf16 (transposed; rows 96..127 unused garbage)
// ---------------------------------------------------------------------------
__global__ __launch_bounds__(256, 3) void gemm_qkv(
    const bf16_t* __restrict__ A, const bf16_t* __restrict__ W,
    const float* __restrict__ bias,
    bf16_t* __restrict__ Qh, bf16_t* __restrict__ Kh, bf16_t* __restrict__ Vt) {
    __shared__ uint4 As4[128 * 8];
    __shared__ uint4 Bs4[128 * 8];
    const int nwg = gridDim.x, cpx = nwg >> 3;   // 1152 -> cpx=144
    const int swz = (blockIdx.x & 7) * cpx + (blockIdx.x >> 3);
    const int m0 = (swz / 18) * 128;
    const int n0 = (swz % 18) * 128;
    const int lane = threadIdx.x & 63, wave = threadIdx.x >> 6;
    const int wr = wave >> 1, wc = wave & 1;
    const int r = lane & 15, q = lane >> 4;
    const int K = DD;

    f32x4 acc[4][4];
#pragma unroll
    for (int i = 0; i < 4; ++i)
#pragma unroll
        for (int j = 0; j < 4; ++j) acc[i][j] = f32x4{0.f, 0.f, 0.f, 0.f};

    for (int k0 = 0; k0 < K; k0 += 64) {
#pragma unroll
        for (int it = 0; it < 4; ++it) {
            int base = it * 256 + wave * 64;
            int c = base + lane;
            int row = c >> 3, pc = c & 7;
            int kc = pc ^ (row & 7);
            load_lds16(A + (size_t)(m0 + row) * K + k0 + kc * 8, &As4[base]);
            load_lds16(W + (size_t)(n0 + row) * K + k0 + kc * 8, &Bs4[base]);
        }
        __syncthreads();
#pragma unroll
        for (int kk = 0; kk < 2; ++kk) {
            bf16x8 af[4], bfr[4];
            int lc = kk * 4 + q;
#pragma unroll
            for (int i = 0; i < 4; ++i) {
                int rowA = wr * 64 + i * 16 + r;
                af[i] = *reinterpret_cast<const bf16x8*>(&As4[rowA * 8 + (lc ^ (rowA & 7))]);
                int rowB = wc * 64 + i * 16 + r;
                bfr[i] = *reinterpret_cast<const bf16x8*>(&Bs4[rowB * 8 + (lc ^ (rowB & 7))]);
            }
#pragma unroll
            for (int i = 0; i < 4; ++i)
#pragma unroll
                for (int j = 0; j < 4; ++j)
                    acc[i][j] = __builtin_amdgcn_mfma_f32_16x16x32_bf16(af[i], bfr[j], acc[i][j], 0, 0, 0);
        }
        __syncthreads();
    }

    const float scale = 0.10206207261596575f;  // 1/sqrt(96)
#pragma unroll
    for (int i = 0; i < 4; ++i) {
#pragma unroll
        for (int j = 0; j < 4; ++j) {
            int cc = n0 + wc * 64 + j * 16 + r;   // 0..2303
            float bv = bias[cc];
            int sec = cc / DD;                    // 0=q 1=k 2=v (uniform per 16-group)
            int within = cc - sec * DD;
            int hh = within / DHH;                // uniform per 16-group (96 = 6*16)
            int dd = within - hh * DHH;
#pragma unroll
            for (int reg = 0; reg < 4; ++reg) {
                int rr = m0 + wr * 64 + i * 16 + q * 4 + reg;  // token
                float v = acc[i][j][reg] + bv;
                int b = rr >> 9, s = rr & 511;
                int bh = b * HH + hh;
                if (sec == 0)
                    Qh[((size_t)bh * SS + s) * 128 + dd] = __float2bfloat16(v * scale);
                else if (sec == 1)
                    Kh[((size_t)bh * SS + s) * 128 + dd] = __float2bfloat16(v);
                else
                    Vt[((size_t)bh * 128 + dd) * SS + s] = __float2bfloat16(v);
            }
        }
    }
}

// ---------------------------------------------------------------------------
// Batched score GEMM: Sc[bh] = Qh[bh] @ Kh[bh]^T   (scale folded into Q)
// M=N=512, K=128 (zero-padded head dim). Skips upper-triangle tiles.
// ---------------------------------------------------------------------------
__global__ __launch_bounds__(256, 3) void gemm_sc(
    const bf16_t* __restrict__ Qh, const bf16_t* __restrict__ Kh,
    bf16_t* __restrict__ Scb) {
    const int bh = blockIdx.z;
    const int m0 = blockIdx.y * 128;
    const int n0 = blockIdx.x * 128;
    if (n0 > m0) return;  // fully above the causal diagonal
    const bf16_t* A = Qh + (size_t)bh * SS * 128;
    const bf16_t* W = Kh + (size_t)bh * SS * 128;
    __shared__ uint4 As4[128 * 8];
    __shared__ uint4 Bs4[128 * 8];
    const int lane = threadIdx.x & 63, wave = threadIdx.x >> 6;
    const int wr = wave >> 1, wc = wave & 1;
    const int r = lane & 15, q = lane >> 4;
    const int K = 128;

    f32x4 acc[4][4];
#pragma unroll
    for (int i = 0; i < 4; ++i)
#pragma unroll
        for (int j = 0; j < 4; ++j) acc[i][j] = f32x4{0.f, 0.f, 0.f, 0.f};

    for (int k0 = 0; k0 < K; k0 += 64) {
#pragma unroll
        for (int it = 0; it < 4; ++it) {
            int base = it * 256 + wave * 64;
            int c = base + lane;
            int row = c >> 3, pc = c & 7;
            int kc = pc ^ (row & 7);
            load_lds16(A + (size_t)(m0 + row) * K + k0 + kc * 8, &As4[base]);
            load_lds16(W + (size_t)(n0 + row) * K + k0 + kc * 8, &Bs4[base]);
        }
        __syncthreads();
#pragma unroll
        for (int kk = 0; kk < 2; ++kk) {
            bf16x8 af[4], bfr[4];
            int lc = kk * 4 + q;
#pragma unroll
            for (int i = 0; i < 4; ++i) {
                int rowA = wr * 64 + i * 16 + r;
                af[i] = *reinterpret_cast<const bf16x8*>(&As4[rowA * 8 + (lc ^ (rowA & 7))]);
                int rowB = wc * 64 + i * 16 + r;
                bfr[i] = *reinterpret_cast<const bf16x8*>(&Bs4[rowB * 8 + (lc ^ (rowB & 7))]);
            }
#pragma unroll
            for (int i = 0; i < 4; ++i)
#pragma unroll
                for (int j = 0; j < 4; ++j)
                    acc[i][j] = __builtin_amdgcn_mfma_f32_16x16x32_bf16(af[i], bfr[j], acc[i][j], 0, 0, 0);
        }
        __syncthreads();
    }

    bf16_t* out = Scb + (size_t)bh * SS * SS;
#pragma unroll
    for (int i = 0; i < 4; ++i) {
#pragma unroll
        for (int j = 0; j < 4; ++j) {
            int cc = n0 + wc * 64 + j * 16 + r;
#pragma unroll
            for (int reg = 0; reg < 4; ++reg) {
                int rr = m0 + wr * 64 + i * 16 + q * 4 + reg;
                out[(size_t)rr * SS + cc] = __float2bfloat16(acc[i][j][reg]);
            }
        }
    }
}

// ---------------------------------------------------------------------------
// Causal softmax in place over bf16 scores. One wave per row of 512.
// ---------------------------------------------------------------------------
__global__ __launch_bounds__(256) void softmax_kernel(bf16_t* __restrict__ Scb) {
    const int wave = threadIdx.x >> 6, lane = threadIdx.x & 63;
    const int row = blockIdx.x * 4 + wave;   // bh*512 + q
    const int qpos = row & (SS - 1);
    const int kn = qpos + 1;
    const int kend = ((qpos >> 7) + 1) << 7;  // 128/256/384/512 (wave-uniform)
    const bool act = (lane << 3) < kend;
    bf16_t* rp = Scb + (size_t)row * SS;
    union {
        uint4 v;
        bf16_t h[8];
    } u;
    float vals[8];
    float m = -1e30f;
    if (act) {
        u.v = *reinterpret_cast<const uint4*>(rp + lane * 8);
#pragma unroll
        for (int e = 0; e < 8; ++e) {
            int j = lane * 8 + e;
            vals[e] = (j < kn) ? __bfloat162float(u.h[e]) : -1e30f;
            m = fmaxf(m, vals[e]);
        }
    } else {
#pragma unroll
        for (int e = 0; e < 8; ++e) vals[e] = -1e30f;
    }
#pragma unroll
    for (int s = 1; s < 64; s <<= 1) m = fmaxf(m, __shfl_xor(m, s));
    float sum = 0.f;
#pragma unroll
    for (int e = 0; e < 8; ++e) {
        vals[e] = __expf(vals[e] - m);
        sum += vals[e];
    }
#pragma unroll
    for (int s = 1; s < 64; s <<= 1) sum += __shfl_xor(sum, s);
    const float inv = 1.f / sum;
    if (act) {
#pragma unroll
        for (int e = 0; e < 8; ++e) u.h[e] = __float2bfloat16(vals[e] * inv);
        *reinterpret_cast<uint4*>(rp + lane * 8) = u.v;
    }
}

// ---------------------------------------------------------------------------
// Batched P@V GEMM: ao[bh rows] = P[bh] @ Vt[bh]^T, causal K-limit.
// ---------------------------------------------------------------------------
__global__ __launch_bounds__(256, 3) void gemm_pv(
    const bf16_t* __restrict__ P, const bf16_t* __restrict__ Vt,
    bf16_t* __restrict__ ao) {
    const int bh = blockIdx.z;
    const int m0 = blockIdx.y * 128;
    const bf16_t* A = P + (size_t)bh * SS * SS;
    const bf16_t* W = Vt + (size_t)bh * 128 * SS;
    __shared__ uint4 As4[128 * 8];
    __shared__ uint4 Bs4[128 * 8];
    const int lane = threadIdx.x & 63, wave = threadIdx.x >> 6;
    const int wr = wave >> 1, wc = wave & 1;
    const int r = lane & 15, q = lane >> 4;
    const int K = SS;
    const int kmax = m0 + 128;

    f32x4 acc[4][4];
#pragma unroll
    for (int i = 0; i < 4; ++i)
#pragma unroll
        for (int j = 0; j < 4; ++j) acc[i][j] = f32x4{0.f, 0.f, 0.f, 0.f};

    for (int k0 = 0; k0 < kmax; k0 += 64) {
#pragma unroll
        for (int it = 0; it < 4; ++it) {
            int base = it * 256 + wave * 64;
            int c = base + lane;
            int row = c >> 3, pc = c & 7;
            int kc = pc ^ (row & 7);
            load_lds16(A + (size_t)(m0 + row) * K + k0 + kc * 8, &As4[base]);
            load_lds16(W + (size_t)row * K + k0 + kc * 8, &Bs4[base]);
        }
        __syncthreads();
#pragma unroll
        for (int kk = 0; kk < 2; ++kk) {
            bf16x8 af[4], bfr[4];
            int lc = kk * 4 + q;
#pragma unroll
            for (int i = 0; i < 4; ++i) {
                int rowA = wr * 64 + i * 16 + r;
                af[i] = *reinterpret_cast<const bf16x8*>(&As4[rowA * 8 + (lc ^ (rowA & 7))]);
                int rowB = wc * 64 + i * 16 + r;
                bfr[i] = *reinterpret_cast<const bf16x8*>(&Bs4[rowB * 8 + (lc ^ (rowB & 7))]);
            }
#pragma unroll
            for (int i = 0; i < 4; ++i)
#pragma unroll
                for (int j = 0; j < 4; ++j)
                    acc[i][j] = __builtin_amdgcn_mfma_f32_16x16x32_bf16(af[i], bfr[j], acc[i][j], 0, 0, 0);
        }
        __syncthreads();
    }

    const int b = bh >> 3, hh = bh & 7;
#pragma unroll
    for (int i = 0; i < 4; ++i) {
#pragma unroll
        for (int j = 0; j < 4; ++j) {
            int cc = wc * 64 + j * 16 + r;  // head dim 0..127
            if (cc < DHH) {
#pragma unroll
                for (int reg = 0; reg < 4; ++reg) {
                    int s = m0 + wr * 64 + i * 16 + q * 4 + reg;
                    size_t t = (size_t)b * SS + s;
                    ao[t * DD + hh * DHH + cc] = __float2bfloat16(acc[i][j][reg]);
                }
            }
        }
    }
}

// ---------------------------------------------------------------------------
// LayerNorm over D=768 of (in + in2). In-place safe. (in2 = split-K partial)
// ---------------------------------------------------------------------------
__global__ __launch_bounds__(256) void ln_kernel(const float* __restrict__ in,
                                                 const float* __restrict__ in2,
                                                 const float* __restrict__ g,
                                                 const float* __restrict__ beta,
                                                 float* __restrict__ xo,
                                                 bf16_t* __restrict__ xb) {
    const int row = blockIdx.x;
    const int tid = threadIdx.x;
    const float* ip = in + (size_t)row * DD;
    const float* ip2 = in2 + (size_t)row * DD;
    float v[3];
#pragma unroll
    for (int t = 0; t < 3; ++t) v[t] = ip[tid + t * 256] + ip2[tid + t * 256];
    float s = v[0] + v[1] + v[2];
    float ss = v[0] * v[0] + v[1] * v[1] + v[2] * v[2];
    for (int off = 32; off > 0; off >>= 1) {
        s += __shfl_down(s, off);
        ss += __shfl_down(ss, off);
    }
    __shared__ float red[8];
    if ((tid & 63) == 0) {
        red[(tid >> 6) * 2] = s;
        red[(tid >> 6) * 2 + 1] = ss;
    }
    __syncthreads();
    s = red[0] + red[2] + red[4] + red[6];
    ss = red[1] + red[3] + red[5] + red[7];
    const float mean = s * (1.f / DD);
    const float var = ss * (1.f / DD) - mean * mean;
    const float rs = rsqrtf(var + 1e-5f);
#pragma unroll
    for (int t = 0; t < 3; ++t) {
        int d = tid + t * 256;
        float y = (v[t] - mean) * rs * g[d] + beta[d];
        xo[(size_t)row * DD + d] = y;
        xb[(size_t)row * DD + d] = __float2bfloat16(y);
    }
}

// ---------------------------------------------------------------------------
// Fused LN1 -> +cv broadcast -> LN2 of (in + in2). Reads once, writes once.
// ---------------------------------------------------------------------------
__global__ __launch_bounds__(256) void ln12_kernel(const float* __restrict__ in,
                                                   const float* __restrict__ in2,
                                                   const float* __restrict__ cvv,
                                                   const float* __restrict__ g1,
                                                   const float* __restrict__ b1,
                                                   const float* __restrict__ g2,
                                                   const float* __restrict__ b2,
                                                   float* __restrict__ xo,
                                                   bf16_t* __restrict__ xb) {
    const int row = blockIdx.x;
    const int tid = threadIdx.x;
    const float* ip = in + (size_t)row * DD;
    const float* ip2 = in2 + (size_t)row * DD;
    const float* cp = cvv + (size_t)(row >> 9) * DD;
    __shared__ float red[8];
    float v[3];
#pragma unroll
    for (int t = 0; t < 3; ++t) v[t] = ip[tid + t * 256] + ip2[tid + t * 256];
    // ---- LN1
    float s = v[0] + v[1] + v[2];
    float ss = v[0] * v[0] + v[1] * v[1] + v[2] * v[2];
    for (int off = 32; off > 0; off >>= 1) {
        s += __shfl_down(s, off);
        ss += __shfl_down(ss, off);
    }
    if ((tid & 63) == 0) {
        red[(tid >> 6) * 2] = s;
        red[(tid >> 6) * 2 + 1] = ss;
    }
    __syncthreads();
    s = red[0] + red[2] + red[4] + red[6];
    ss = red[1] + red[3] + red[5] + red[7];
    float mean = s * (1.f / DD);
    float var = ss * (1.f / DD) - mean * mean;
    float rs = rsqrtf(var + 1e-5f);
#pragma unroll
    for (int t = 0; t < 3; ++t) {
        int d = tid + t * 256;
        v[t] = (v[t] - mean) * rs * g1[d] + b1[d] + cp[d];
    }
    // ---- LN2
    s = v[0] + v[1] + v[2];
    ss = v[0] * v[0] + v[1] * v[1] + v[2] * v[2];
    for (int off = 32; off > 0; off >>= 1) {
        s += __shfl_down(s, off);
        ss += __shfl_down(ss, off);
    }
    __syncthreads();  // protect red reuse
    if ((tid & 63) == 0) {
        red[(tid >> 6) * 2] = s;
        red[(tid >> 6) * 2 + 1] = ss;
    }
    __syncthreads();
    s = red[0] + red[2] + red[4] + red[6];
    ss = red[1] + red[3] + red[5] + red[7];
    mean = s * (1.f / DD);
    var = ss * (1.f / DD) - mean * mean;
    rs = rsqrtf(var + 1e-5f);
#pragma unroll
    for (int t = 0; t < 3; ++t) {
        int d = tid + t * 256;
        float y = (v[t] - mean) * rs * g2[d] + b2[d];
        xo[(size_t)row * DD + d] = y;
        xb[(size_t)row * DD + d] = __float2bfloat16(y);
    }
}

// ---------------------------------------------------------------------------
// Host launcher
// ---------------------------------------------------------------------------
extern "C" void kernel_launch(void* const* d_in, const int* in_sizes, int n_in,
                              void* d_out, int out_size, void* d_ws, size_t ws_size,
                              hipStream_t stream) {
    (void)in_sizes; (void)n_in; (void)out_size; (void)ws_size;
    const float* latent   = (const float*)d_in[0];
    const int*   target   = (const int*)d_in[1];
    const float* tok_emb  = (const float*)d_in[2];
    const float* pos_emb  = (const float*)d_in[3];
    const float* sa_w_qkv = (const float*)d_in[4];
    const float* sa_b_qkv = (const float*)d_in[5];
    const float* sa_w_o   = (const float*)d_in[6];
    const float* sa_b_o   = (const float*)d_in[7];
    const float* ca_w_qkv = (const float*)d_in[8];
    const float* ca_b_qkv = (const float*)d_in[9];
    const float* ca_w_o   = (const float*)d_in[10];
    const float* ca_b_o   = (const float*)d_in[11];
    const float* ffn_w1   = (const float*)d_in[12];
    const float* ffn_b1   = (const float*)d_in[13];
    const float* ffn_w2   = (const float*)d_in[14];
    const float* ffn_b2   = (const float*)d_in[15];
    const float* ln1_g    = (const float*)d_in[16];
    const float* ln1_b    = (const float*)d_in[17];
    const float* ln2_g    = (const float*)d_in[18];
    const float* ln2_b    = (const float*)d_in[19];
    const float* ln3_g    = (const float*)d_in[20];
    const float* ln3_b    = (const float*)d_in[21];
    const float* out_w    = (const float*)d_in[22];
    const float* out_b    = (const float*)d_in[23];
    float* out = (float*)d_out;

    // workspace carve-up (256B aligned)
    char* ws = (char*)d_ws;
    size_t off = 0;
    auto alloc = [&](size_t bytes) {
        void* p = ws + off;
        off += (bytes + 255) & ~(size_t)255;
        return p;
    };
    float*  x    = (float*)alloc((size_t)TT * DD * 4);        // residual stream fp32
    bf16_t* xb   = (bf16_t*)alloc((size_t)TT * DD * 2);       // bf16 shadow
    bf16_t* ao   = (bf16_t*)alloc((size_t)TT * DD * 2);       // attn out bf16
    float*  cv   = (float*)alloc((size_t)LL * BB * DD * 4);   // cross-attn vectors
    float*  v16  = (float*)alloc((size_t)LL * BB * DD * 4);   // cv stage-1 temp
    bf16_t* wqkv_b = (bf16_t*)alloc((size_t)LL * 3 * DD * DD * 2);
    bf16_t* wo_b   = (bf16_t*)alloc((size_t)LL * DD * DD * 2);
    bf16_t* w1_b   = (bf16_t*)alloc((size_t)LL * FF * DD * 2);
    bf16_t* w2_b   = (bf16_t*)alloc((size_t)LL * DD * FF * 2);
    bf16_t* wout_b = (bf16_t*)alloc((size_t)128 * DD * 2);
    // Attention region:
    //   Qh [128][512][128] bf16 (16.78 MB)  pad cols 96..127 zero (re-zeroed/layer)
    //   Kh [128][512][128] bf16 (16.78 MB)  pad cols 96..127 zero (re-zeroed/layer)
    //   Vt [128][128][512] bf16 (16.78 MB)  rows 96..127 unused garbage (guarded)
    //   Scb[128][512][512] bf16 (67.1 MB)   scores, then P in place
    char* attnR = (char*)alloc((size_t)BH * SS * 128 * 2 * 3 + (size_t)BH * SS * SS * 2);
    bf16_t* Qh  = (bf16_t*)attnR;
    bf16_t* Kh  = Qh + (size_t)BH * SS * 128;
    bf16_t* Vt  = Kh + (size_t)BH * SS * 128;
    bf16_t* Scb = Vt + (size_t)BH * 128 * SS;
    // FFN-phase overlays:
    //   h    [T,2048] bf16 (33.55 MB) -> Qh+Kh region (exactly 2x16.78 MB;
    //        trashes pad cols -> zero_pads_kernel re-zeroes at next layer top)
    //   tmp2 [T,768] fp32 (25.2 MB)   -> Scb[0, 25.2 MB)  (P dead after pv)
    //   tmp  [T,768] fp32 (25.2 MB)   -> Scb + 34 MB
    bf16_t* h    = Qh;
    float*  tmp2 = (float*)Scb;
    float*  tmp  = (float*)((char*)Scb + ((size_t)34 << 20));

    // weight conversions (every call: ws is re-poisoned)
    cvt8_kernel<<<2048, 256, 0, stream>>>((const float4*)sa_w_qkv, (uint4*)wqkv_b, LL * 3 * DD * DD / 8);
    cvt8_kernel<<<2048, 256, 0, stream>>>((const float4*)sa_w_o, (uint4*)wo_b, LL * DD * DD / 8);
    cvt8_kernel<<<2048, 256, 0, stream>>>((const float4*)ffn_w1, (uint4*)w1_b, LL * FF * DD / 8);
    cvt8_kernel<<<2048, 256, 0, stream>>>((const float4*)ffn_w2, (uint4*)w2_b, LL * DD * FF / 8);
    pad_wout_kernel<<<(128 * DD) / 256, 256, 0, stream>>>(out_w, wout_b);
    // zero Qh+Kh fully once (covers layer-0 pads; later layers use zero_pads)
    {
        int n4 = (int)(((size_t)BH * SS * 128 * 2 * 2) / 16);  // uint4 count
        fill_zero_kernel<<<(n4 + 255) / 256, 256, 0, stream>>>((uint4*)Qh, n4);
    }

    // collapsed cross-attention: v16 = latent @ Wv^T + bv; cv = v16 @ Wo^T + bo
    cvmm_kernel<<<dim3(DD / 16, LL), 256, 0, stream>>>(
        latent, 0, ca_w_qkv, (size_t)3 * DD * DD, (size_t)2 * DD * DD,
        ca_b_qkv, (size_t)3 * DD, (size_t)2 * DD, v16);
    cvmm_kernel<<<dim3(DD / 16, LL), 256, 0, stream>>>(
        v16, BB * DD, ca_w_o, (size_t)DD * DD, 0,
        ca_b_o, (size_t)DD, 0, cv);

    // embeddings
    embed_kernel<<<TT, 256, 0, stream>>>(target, tok_emb, pos_emb, x, xb);

    for (int i = 0; i < LL; ++i) {
        // re-zero Qh/Kh pad columns (trashed by previous layer's h overlay)
        if (i) zero_pads_kernel<<<2048, 256, 0, stream>>>(Qh, Kh);
        // QKV projection -> Qh/Kh/Vt (1D grid 1152, XCD-swizzled)
        gemm_qkv<<<dim3(1152), 256, 0, stream>>>(
            xb, wqkv_b + (size_t)i * 3 * DD * DD, sa_b_qkv + (size_t)i * 3 * DD,
            Qh, Kh, Vt);
        // scores (lower-triangle tiles only)
        gemm_sc<<<dim3(4, 4, BH), 256, 0, stream>>>(Qh, Kh, Scb);
        // causal softmax in place -> P
        softmax_kernel<<<(BH * SS) / 4, 256, 0, stream>>>(Scb);
        // P @ V -> ao (causal K-limit)
        gemm_pv<<<dim3(1, 4, BH), 256, 0, stream>>>(Scb, Vt, ao);
        // O projection, split-K=2: z0 -> tmp (bias + x resid), z1 -> tmp2
        gemm_bt<false, false, true><<<dim3(384, 1, 2), 256, 0, stream>>>(
            ao, wo_b + (size_t)i * DD * DD, sa_b_o + (size_t)i * DD,
            x, tmp, nullptr, tmp2, DD, DD / 2, DD, DD, 6);
        // LN1 + cv + LN2 fused over (tmp + tmp2) -> x, xb
        ln12_kernel<<<TT, 256, 0, stream>>>(tmp, tmp2, cv + (size_t)i * BB * DD,
                                            ln1_g + (size_t)i * DD, ln1_b + (size_t)i * DD,
                                            ln2_g + (size_t)i * DD, ln2_b + (size_t)i * DD,
                                            x, xb);
        // FFN1: relu(x@W1^T+b1) -> h (bf16, Qh+Kh overlay); grid 1024 swizzled
        gemm_bt<true, true, false><<<dim3(1024, 1, 1), 256, 0, stream>>>(
            xb, w1_b + (size_t)i * FF * DD, ffn_b1 + (size_t)i * FF,
            nullptr, nullptr, h, nullptr, DD, DD, FF, FF, 16);
        // FFN2, split-K=2: z0 -> tmp (bias + x resid), z1 -> tmp2
        gemm_bt<false, false, true><<<dim3(384, 1, 2), 256, 0, stream>>>(
            h, w2_b + (size_t)i * DD * FF, ffn_b2 + (size_t)i * DD,
            x, tmp, nullptr, tmp2, FF, FF / 2, DD, DD, 6);
        // LN3 over (tmp + tmp2) -> x, xb
        ln_kernel<<<TT, 256, 0, stream>>>(tmp, tmp2, ln3_g + (size_t)i * DD,
                                          ln3_b + (size_t)i * DD, x, xb);
    }

    // final projection to logits [8192,100] (padded N=128, guarded; grid 64)
    gemm_bt<false, false, false><<<dim3(64, 1, 1), 256, 0, stream>>>(
        xb, wout_b, out_b, nullptr, out, nullptr, nullptr, DD, DD, VV, VV, 1);
}